// Round 13
// baseline (764.581 us; speedup 1.0000x reference)
//
#include <hip/hip_runtime.h>

#define N_NODES 50000
#define N_EDGES 800000
#define N_FEAT  128
#define N_HID   64

#define BKT_LOG 8
#define BKT_SZ  256                                  // nodes per bucket
#define NBKT    ((N_NODES + BKT_SZ - 1) / BKT_SZ)    // 196
#define CH      4096                                 // edges per partition block
#define NB1     ((N_EDGES + CH - 1) / CH)            // 196
#define GROWS   64                                   // rows per gemm block
#define GG      ((N_NODES + GROWS - 1) / GROWS)      // 782 gemm blocks

__device__ inline void fma4(float4& acc, float s, const float4& w) {
    acc.x = fmaf(s, w.x, acc.x);
    acc.y = fmaf(s, w.y, acc.y);
    acc.z = fmaf(s, w.z, acc.z);
    acc.w = fmaf(s, w.w, acc.w);
}

__device__ inline unsigned short f2bf(float f) {          // RNE f32 -> bf16
    unsigned u = __float_as_uint(f);
    u = u + 0x7FFFu + ((u >> 16) & 1u);
    return (unsigned short)(u >> 16);
}

__device__ inline int wave_incl_scan(int v) {
    int lane = threadIdx.x & 63;
#pragma unroll
    for (int o = 1; o < 64; o <<= 1) {
        int u = __shfl_up(v, o);
        if (lane >= o) v += u;
    }
    return v;
}

// ---------- gemm core: 2 rows x 8 cols per thread, 64 rows/block ----------
template <int K>
__device__ inline void gemm_body(const float* __restrict__ a, const float* __restrict__ lw,
                                 unsigned short* __restrict__ o, int blk) {
    int tid = threadIdx.x;
    int rp = tid >> 3;                 // 0..31
    int c0 = (tid & 7) * 8;            // 0,8,...,56
    int row0 = blk * GROWS + rp * 2;
    if (row0 >= N_NODES) return;
    bool two = (row0 + 1) < N_NODES;

    const float* a0 = a + (long)row0 * K;
    const float* a1 = two ? (a0 + K) : a0;

    float4 aA0 = make_float4(0.f, 0.f, 0.f, 0.f), aA1 = aA0;
    float4 aB0 = aA0, aB1 = aA0;

#pragma unroll 4
    for (int k4 = 0; k4 < K / 4; ++k4) {
        float4 xa = *(const float4*)(a0 + k4 * 4);
        float4 xb = *(const float4*)(a1 + k4 * 4);
#pragma unroll
        for (int j = 0; j < 4; ++j) {
            const float* wk = &lw[(k4 * 4 + j) * N_HID + c0];
            float4 w0 = *(const float4*)(wk);
            float4 w1 = *(const float4*)(wk + 4);
            float sa = (j == 0) ? xa.x : (j == 1) ? xa.y : (j == 2) ? xa.z : xa.w;
            float sb = (j == 0) ? xb.x : (j == 1) ? xb.y : (j == 2) ? xb.z : xb.w;
            fma4(aA0, sa, w0); fma4(aA1, sa, w1);
            fma4(aB0, sb, w0); fma4(aB1, sb, w1);
        }
    }

    unsigned short* op = o + (long)row0 * N_HID + c0;
    *(ushort4*)op = make_ushort4(f2bf(aA0.x), f2bf(aA0.y), f2bf(aA0.z), f2bf(aA0.w));
    *(ushort4*)(op + 4) = make_ushort4(f2bf(aA1.x), f2bf(aA1.y), f2bf(aA1.z), f2bf(aA1.w));
    if (two) {
        *(ushort4*)(op + N_HID) = make_ushort4(f2bf(aB0.x), f2bf(aB0.y), f2bf(aB0.z), f2bf(aB0.w));
        *(ushort4*)(op + N_HID + 4) = make_ushort4(f2bf(aB1.x), f2bf(aB1.y), f2bf(aB1.z), f2bf(aB1.w));
    }
}

// ---------- K1: gemm1 (x@w1 -> bf16 hwb) fused with binhist ----------
__global__ __launch_bounds__(256) void gemm1_hist(const float* __restrict__ a,
                                                  const float* __restrict__ w,
                                                  unsigned short* __restrict__ o,
                                                  const int* __restrict__ dst,
                                                  int* __restrict__ cnt,
                                                  int* __restrict__ cnt_t) {
    __shared__ float lw[N_FEAT * N_HID];        // 32 KB
    int tid = threadIdx.x;
    if (blockIdx.x < NB1) {                      // ---- histogram part ----
        int* h = (int*)lw;                       // reuse LDS
        int bid = blockIdx.x;
        if (tid < NBKT) h[tid] = 0;
        __syncthreads();
        int e0 = bid * CH;
        for (int i = tid; i < CH; i += 256) {
            int e = e0 + i;
            if (e < N_EDGES) atomicAdd(&h[dst[e] >> BKT_LOG], 1);
        }
        __syncthreads();
        if (tid < NBKT) {
            int v = h[tid];
            cnt[bid * NBKT + tid] = v;
            cnt_t[tid * NB1 + bid] = v;
        }
        return;
    }
    // ---- gemm part ----
    for (int idx = tid * 4; idx < N_FEAT * N_HID; idx += 256 * 4)
        *(float4*)&lw[idx] = *(const float4*)&w[idx];
    __syncthreads();
    gemm_body<N_FEAT>(a, lw, o, blockIdx.x - NB1);
}

// ---------- tiled GEMM (f32 in, bf16 out), layer 2 ----------
template <int K>
__global__ __launch_bounds__(256) void gemm_tile(const float* __restrict__ a,
                                                 const float* __restrict__ w,
                                                 unsigned short* __restrict__ o) {
    __shared__ float lw[K * N_HID];
    int tid = threadIdx.x;
    for (int idx = tid * 4; idx < K * N_HID; idx += 256 * 4)
        *(float4*)&lw[idx] = *(const float4*)&w[idx];
    __syncthreads();
    gemm_body<K>(a, lw, o, blockIdx.x);
}

// ---------- K2: binscatter, self-computing cursor bases (4-wave scan) ----------
__global__ __launch_bounds__(256) void binscatter(const int* __restrict__ src,
                                                  const int* __restrict__ dst,
                                                  const float* __restrict__ ew,
                                                  const int* __restrict__ cnt,
                                                  const int* __restrict__ cnt_t,
                                                  uint2* __restrict__ slab) {
    __shared__ int cur[NBKT];
    __shared__ int wtot[4];
    int t = threadIdx.x;
    int b = blockIdx.x;

    int tot = 0, pre = 0;
    if (t < NBKT) {
        const int4* p = (const int4*)(cnt_t + t * NB1);   // NB1 % 4 == 0
        for (int q = 0; q < NB1 / 4; ++q) {
            int4 v = p[q];
            tot += v.x + v.y + v.z + v.w;
        }
        int p0 = 0, p1 = 0, p2 = 0, p3 = 0;
        int j = 0;
        for (; j + 4 <= b; j += 4) {
            p0 += cnt[(j + 0) * NBKT + t];
            p1 += cnt[(j + 1) * NBKT + t];
            p2 += cnt[(j + 2) * NBKT + t];
            p3 += cnt[(j + 3) * NBKT + t];
        }
        for (; j < b; ++j) p0 += cnt[j * NBKT + t];
        pre = p0 + p1 + p2 + p3;
    }
    int incl = wave_incl_scan(tot);
    if ((t & 63) == 63) wtot[t >> 6] = incl;
    __syncthreads();
    if (t < NBKT) {
        int wv = t >> 6;
        int add = 0;
#pragma unroll
        for (int i = 0; i < 4; ++i) add += (i < wv) ? wtot[i] : 0;
        cur[t] = add + incl - tot + pre;          // bucket base + per-block offset
    }
    __syncthreads();

    int e0 = b * CH;
    for (int i = t; i < CH; i += 256) {
        int e = e0 + i;
        if (e >= N_EDGES) continue;
        int d = dst[e];
        int bin = d >> BKT_LOG;
        int p = atomicAdd(&cur[bin], 1);
        slab[p] = make_uint2((unsigned)src[e] | ((unsigned)(d & (BKT_SZ - 1)) << 16),
                             __float_as_uint(ew[e]));
    }
}

// ---------- K3/K5: per-bucket LDS-accumulate aggregation ----------
// block = bucket (256 nodes, 64KB f32 accumulator). Streams its slab segment:
// per edge, 8 lanes x 16B gather of the bf16 row, ds_add_f32 into swizzled LDS.
template <bool RELU>
__global__ __launch_bounds__(512) void bucket_agg(const unsigned short* __restrict__ hwb,
                                                  const uint2* __restrict__ slab,
                                                  const int* __restrict__ cnt_t,
                                                  const float* __restrict__ bias,
                                                  float* __restrict__ outp) {
    __shared__ float acc[BKT_SZ * N_HID];      // 64 KB
    __shared__ int tt[NBKT];
    __shared__ int bs[2];
    int t = threadIdx.x;
    int b = blockIdx.x;

    if (t < NBKT) {
        int s = 0;
        const int4* p = (const int4*)(cnt_t + t * NB1);
        for (int q = 0; q < NB1 / 4; ++q) {
            int4 v = p[q];
            s += v.x + v.y + v.z + v.w;
        }
        tt[t] = s;
    }
    __syncthreads();
    if (t < 64) {
        int v = 0;
        for (int k = t; k < NBKT; k += 64) v += (k < b) ? tt[k] : 0;
#pragma unroll
        for (int o = 32; o >= 1; o >>= 1) v += __shfl_xor(v, o);
        if (t == 0) { bs[0] = v; bs[1] = tt[b]; }
    }
    for (int i = t * 4; i < BKT_SZ * N_HID; i += 512 * 4)
        *(float4*)&acc[i] = make_float4(0.f, 0.f, 0.f, 0.f);
    __syncthreads();
    int base = bs[0];
    int c = bs[1];

    int f8 = (t & 7) * 8;                       // feature group of this lane
    for (int i = (t >> 3); i < c; i += 64) {    // 64 edges per trip per block
        uint2 e = slab[base + i];
        int srcn = (int)(e.x & 0xFFFFu);
        int dlow = (int)((e.x >> 16) & (BKT_SZ - 1));
        float w = __uint_as_float(e.y);
        uint4 v = *(const uint4*)&hwb[(long)srcn * N_HID + f8];
        float* ap = &acc[dlow * N_HID + (f8 ^ ((dlow & 7) << 3))];
        atomicAdd(ap + 0, w * __uint_as_float(v.x << 16));
        atomicAdd(ap + 1, w * __uint_as_float(v.x & 0xFFFF0000u));
        atomicAdd(ap + 2, w * __uint_as_float(v.y << 16));
        atomicAdd(ap + 3, w * __uint_as_float(v.y & 0xFFFF0000u));
        atomicAdd(ap + 4, w * __uint_as_float(v.z << 16));
        atomicAdd(ap + 5, w * __uint_as_float(v.z & 0xFFFF0000u));
        atomicAdd(ap + 6, w * __uint_as_float(v.w << 16));
        atomicAdd(ap + 7, w * __uint_as_float(v.w & 0xFFFF0000u));
    }
    __syncthreads();

    // writeback: un-swizzle, + bias (+ReLU), coalesced f32 rows
    int node0 = b << BKT_LOG;
    for (int u = t; u < BKT_SZ * 8; u += 512) {
        int n = u >> 3;
        int g = u & 7;
        int gn = node0 + n;
        if (gn >= N_NODES) break;               // n monotone per thread
        int gs = (g ^ (n & 7)) * 8;
        float4 v0 = *(float4*)&acc[n * N_HID + gs];
        float4 v1 = *(float4*)&acc[n * N_HID + gs + 4];
        float4 b0 = *(const float4*)&bias[g * 8];
        float4 b1v = *(const float4*)&bias[g * 8 + 4];
        v0.x += b0.x;  v0.y += b0.y;  v0.z += b0.z;  v0.w += b0.w;
        v1.x += b1v.x; v1.y += b1v.y; v1.z += b1v.z; v1.w += b1v.w;
        if (RELU) {
            v0.x = fmaxf(v0.x, 0.f); v0.y = fmaxf(v0.y, 0.f);
            v0.z = fmaxf(v0.z, 0.f); v0.w = fmaxf(v0.w, 0.f);
            v1.x = fmaxf(v1.x, 0.f); v1.y = fmaxf(v1.y, 0.f);
            v1.z = fmaxf(v1.z, 0.f); v1.w = fmaxf(v1.w, 0.f);
        }
        *(float4*)&outp[(long)gn * N_HID + g * 8] = v0;
        *(float4*)&outp[(long)gn * N_HID + g * 8 + 4] = v1;
    }
}

extern "C" void kernel_launch(void* const* d_in, const int* in_sizes, int n_in,
                              void* d_out, int out_size, void* d_ws, size_t ws_size,
                              hipStream_t stream) {
    const float* x  = (const float*)d_in[0];
    const int*   ei = (const int*)d_in[1];   // [2, E] flat: src then dst
    const float* ew = (const float*)d_in[2];
    const float* w1 = (const float*)d_in[3];
    const float* b1 = (const float*)d_in[4];
    const float* w2 = (const float*)d_in[5];
    const float* b2 = (const float*)d_in[6];
    float* out = (float*)d_out;

    const int* src = ei;
    const int* dst = ei + N_EDGES;

    char* ws = (char*)d_ws;
    unsigned short* hwb  = (unsigned short*)ws;                      // 6.4 MB
    unsigned short* hwb2 = (unsigned short*)(ws + (size_t)7  * 1024 * 1024); // 6.4 MB
    uint2*    slab  = (uint2*)   (ws + (size_t)14 * 1024 * 1024);    // 6.4 MB
    int*      cnt   = (int*)     (ws + (size_t)21 * 1024 * 1024);    // NB1*NBKT
    int*      cnt_t = cnt + NB1 * NBKT;                              // NBKT*NB1

    dim3 blk(256);

    // K1: hist blocks first, then gemm1 blocks (one launch, parallel)
    gemm1_hist<<<dim3(NB1 + GG), blk, 0, stream>>>(x, w1, hwb, dst, cnt, cnt_t);
    // K2: bucket partition (self-computed offsets), f32 weights kept
    binscatter<<<dim3(NB1), blk, 0, stream>>>(src, dst, ew, cnt, cnt_t, slab);
    // K3: layer-1 aggregation via LDS accumulators -> h (f32, staged in d_out)
    bucket_agg<true><<<dim3(NBKT), dim3(512), 0, stream>>>(hwb, slab, cnt_t, b1, out);
    // K4: gemm2: h @ w2 -> bf16 hwb2
    gemm_tile<N_HID><<<dim3(GG), blk, 0, stream>>>(out, w2, hwb2);
    // K5: layer-2 aggregation -> out (f32)
    bucket_agg<false><<<dim3(NBKT), dim3(512), 0, stream>>>(hwb2, slab, cnt_t, b2, out);
}

// Round 14
// 143.715 us; speedup vs baseline: 5.3201x; 5.3201x over previous
//
#include <hip/hip_runtime.h>

#define N_NODES 50000
#define N_EDGES 800000
#define N_FEAT  128
#define N_HID   64

#define BKT_LOG 9
#define BKT_SZ  512                                  // nodes per bucket
#define NBKT    ((N_NODES + BKT_SZ - 1) / BKT_SZ)    // 98
#define CH      4096                                 // edges per partition block
#define NB1     ((N_EDGES + CH - 1) / CH)            // 196
#define GROWS   64                                   // rows per gemm block
#define GG      ((N_NODES + GROWS - 1) / GROWS)      // 782 gemm blocks
#define AGG_B   2048                                 // agg grid (grid-stride)

__device__ inline void fma4(float4& acc, float s, const float4& w) {
    acc.x = fmaf(s, w.x, acc.x);
    acc.y = fmaf(s, w.y, acc.y);
    acc.z = fmaf(s, w.z, acc.z);
    acc.w = fmaf(s, w.w, acc.w);
}

__device__ inline unsigned short f2bf(float f) {          // RNE f32 -> bf16
    unsigned u = __float_as_uint(f);
    u = u + 0x7FFFu + ((u >> 16) & 1u);
    return (unsigned short)(u >> 16);
}
__device__ inline float bf2f(unsigned short v) { return __uint_as_float(((unsigned)v) << 16); }

__device__ inline int wave_incl_scan(int v) {
    int lane = threadIdx.x & 63;
#pragma unroll
    for (int o = 1; o < 64; o <<= 1) {
        int u = __shfl_up(v, o);
        if (lane >= o) v += u;
    }
    return v;
}

// ---------- gemm core: 2 rows x 8 cols per thread, 64 rows/block ----------
template <int K>
__device__ inline void gemm_body(const float* __restrict__ a, const float* __restrict__ lw,
                                 unsigned short* __restrict__ o, int blk) {
    int tid = threadIdx.x;
    int rp = tid >> 3;                 // 0..31
    int c0 = (tid & 7) * 8;            // 0,8,...,56
    int row0 = blk * GROWS + rp * 2;
    if (row0 >= N_NODES) return;
    bool two = (row0 + 1) < N_NODES;

    const float* a0 = a + (long)row0 * K;
    const float* a1 = two ? (a0 + K) : a0;

    float4 aA0 = make_float4(0.f, 0.f, 0.f, 0.f), aA1 = aA0;
    float4 aB0 = aA0, aB1 = aA0;

#pragma unroll 4
    for (int k4 = 0; k4 < K / 4; ++k4) {
        float4 xa = *(const float4*)(a0 + k4 * 4);
        float4 xb = *(const float4*)(a1 + k4 * 4);
#pragma unroll
        for (int j = 0; j < 4; ++j) {
            const float* wk = &lw[(k4 * 4 + j) * N_HID + c0];
            float4 w0 = *(const float4*)(wk);
            float4 w1 = *(const float4*)(wk + 4);
            float sa = (j == 0) ? xa.x : (j == 1) ? xa.y : (j == 2) ? xa.z : xa.w;
            float sb = (j == 0) ? xb.x : (j == 1) ? xb.y : (j == 2) ? xb.z : xb.w;
            fma4(aA0, sa, w0); fma4(aA1, sa, w1);
            fma4(aB0, sb, w0); fma4(aB1, sb, w1);
        }
    }

    unsigned short* op = o + (long)row0 * N_HID + c0;
    *(ushort4*)op = make_ushort4(f2bf(aA0.x), f2bf(aA0.y), f2bf(aA0.z), f2bf(aA0.w));
    *(ushort4*)(op + 4) = make_ushort4(f2bf(aA1.x), f2bf(aA1.y), f2bf(aA1.z), f2bf(aA1.w));
    if (two) {
        *(ushort4*)(op + N_HID) = make_ushort4(f2bf(aB0.x), f2bf(aB0.y), f2bf(aB0.z), f2bf(aB0.w));
        *(ushort4*)(op + N_HID + 4) = make_ushort4(f2bf(aB1.x), f2bf(aB1.y), f2bf(aB1.z), f2bf(aB1.w));
    }
}

// ---------- K1: gemm1 (x@w1 -> bf16 hwb) fused with binhist ----------
__global__ __launch_bounds__(256) void gemm1_hist(const float* __restrict__ a,
                                                  const float* __restrict__ w,
                                                  unsigned short* __restrict__ o,
                                                  const int* __restrict__ dst,
                                                  int* __restrict__ cnt,
                                                  int* __restrict__ cnt_t) {
    __shared__ float lw[N_FEAT * N_HID];        // 32 KB
    int tid = threadIdx.x;
    if (blockIdx.x < NB1) {                      // ---- histogram part ----
        int* h = (int*)lw;                       // reuse LDS
        int bid = blockIdx.x;
        if (tid < NBKT) h[tid] = 0;
        __syncthreads();
        int e0 = bid * CH;
        for (int i = tid; i < CH; i += 256) {
            int e = e0 + i;
            if (e < N_EDGES) atomicAdd(&h[dst[e] >> BKT_LOG], 1);
        }
        __syncthreads();
        if (tid < NBKT) {
            int v = h[tid];
            cnt[bid * NBKT + tid] = v;
            cnt_t[tid * NB1 + bid] = v;
        }
        return;
    }
    // ---- gemm part ----
    for (int idx = tid * 4; idx < N_FEAT * N_HID; idx += 256 * 4)
        *(float4*)&lw[idx] = *(const float4*)&w[idx];
    __syncthreads();
    gemm_body<N_FEAT>(a, lw, o, blockIdx.x - NB1);
}

// ---------- K2: binscatter, self-computing cursor bases ----------
__global__ __launch_bounds__(256) void binscatter(const int* __restrict__ src,
                                                  const int* __restrict__ dst,
                                                  const float* __restrict__ ew,
                                                  const int* __restrict__ cnt,
                                                  const int* __restrict__ cnt_t,
                                                  uint2* __restrict__ slab) {
    __shared__ int cur[NBKT];
    __shared__ int wtot[2];
    int t = threadIdx.x;
    int b = blockIdx.x;

    int tot = 0, pre = 0;
    if (t < NBKT) {
        const int4* p = (const int4*)(cnt_t + t * NB1);   // NB1 % 4 == 0
        for (int q = 0; q < NB1 / 4; ++q) {
            int4 v = p[q];
            tot += v.x + v.y + v.z + v.w;
        }
        int p0 = 0, p1 = 0, p2 = 0, p3 = 0;
        int j = 0;
        for (; j + 4 <= b; j += 4) {
            p0 += cnt[(j + 0) * NBKT + t];
            p1 += cnt[(j + 1) * NBKT + t];
            p2 += cnt[(j + 2) * NBKT + t];
            p3 += cnt[(j + 3) * NBKT + t];
        }
        for (; j < b; ++j) p0 += cnt[j * NBKT + t];
        pre = p0 + p1 + p2 + p3;
    }
    int incl = wave_incl_scan(tot);                   // waves 0,1 cover t<98
    if (t < 128 && (t & 63) == 63) wtot[t >> 6] = incl;
    __syncthreads();
    if (t < NBKT) {
        int bstart_t = (t >= 64 ? wtot[0] : 0) + incl - tot;  // exclusive prefix
        cur[t] = bstart_t + pre;
    }
    __syncthreads();

    int e0 = b * CH;
    for (int i = t; i < CH; i += 256) {
        int e = e0 + i;
        if (e >= N_EDGES) continue;
        int d = dst[e];
        int bin = d >> BKT_LOG;
        int p = atomicAdd(&cur[bin], 1);
        slab[p] = make_uint2((unsigned)src[e] | ((unsigned)(d & (BKT_SZ - 1)) << 16),
                             __float_as_uint(ew[e]));
    }
}

// ---------- K3: per-bucket counting sort (self-computed bstart, wave scans) ----------
__global__ __launch_bounds__(512) void sort_bucket(const uint2* __restrict__ slab,
                                                   const int* __restrict__ cnt_t,
                                                   unsigned* __restrict__ edges,
                                                   int* __restrict__ start) {
    __shared__ int tt[NBKT];
    __shared__ int h[BKT_SZ];
    __shared__ int wtot[8];
    __shared__ int bs[2];
    int b = blockIdx.x;
    int t = threadIdx.x;
    int lane = t & 63;
    int w = t >> 6;

    if (t < NBKT) {
        int s = 0;
        const int4* p = (const int4*)(cnt_t + t * NB1);
        for (int q = 0; q < NB1 / 4; ++q) {
            int4 v = p[q];
            s += v.x + v.y + v.z + v.w;
        }
        tt[t] = s;
    }
    __syncthreads();
    if (t < 64) {
        int v = (t < b ? tt[t] : 0) + (t + 64 < b ? tt[t + 64] : 0);
#pragma unroll
        for (int o = 32; o >= 1; o >>= 1) v += __shfl_xor(v, o);
        if (t == 0) { bs[0] = v; bs[1] = tt[b]; }
    }
    __syncthreads();
    int base = bs[0];
    int c = bs[1];

    h[t] = 0;
    __syncthreads();
    for (int i = t; i < c; i += 512)
        atomicAdd(&h[(slab[base + i].x >> 16) & (BKT_SZ - 1)], 1);
    __syncthreads();

    int v = h[t];
    int incl = wave_incl_scan(v);
    if (lane == 63) wtot[w] = incl;
    __syncthreads();
    int add = 0;
#pragma unroll
    for (int i = 0; i < 8; ++i) add += (i < w) ? wtot[i] : 0;
    int excl = add + incl - v;

    int g = (b << BKT_LOG) + t;
    if (g < N_NODES) start[g] = base + excl;
    if (b == NBKT - 1 && t == 0) start[N_NODES] = N_EDGES;

    h[t] = base + excl;                   // reuse as cursor
    __syncthreads();
    for (int i = t; i < c; i += 512) {
        uint2 r = slab[base + i];
        int p = atomicAdd(&h[(r.x >> 16) & (BKT_SZ - 1)], 1);
        edges[p] = (r.x & 0xFFFFu) | ((unsigned)f2bf(__uint_as_float(r.y)) << 16);
    }
}

// ---------- agg core ----------
__device__ inline float4 agg_core(const unsigned short* __restrict__ hwb,
                                  const unsigned* __restrict__ edges,
                                  int i0, int i1, int es, int f4) {
    float4 acc = make_float4(0.f, 0.f, 0.f, 0.f);
    for (int base = i0; base < i1; base += 16) {
        int ia = base + es;
        int ib = base + 4 + es;
        int ic = base + 8 + es;
        int id = base + 12 + es;
        float wa = 0.f, wb = 0.f, wc = 0.f, wd = 0.f;
        float4 va = make_float4(0.f, 0.f, 0.f, 0.f);
        float4 vb = va, vc = va, vd = va;
        if (ia < i1) {
            unsigned e = edges[ia];
            wa = __uint_as_float(e & 0xFFFF0000u);
            ushort4 v = *(const ushort4*)&hwb[(long)(e & 0xFFFFu) * N_HID + f4];
            va = make_float4(bf2f(v.x), bf2f(v.y), bf2f(v.z), bf2f(v.w));
        }
        if (ib < i1) {
            unsigned e = edges[ib];
            wb = __uint_as_float(e & 0xFFFF0000u);
            ushort4 v = *(const ushort4*)&hwb[(long)(e & 0xFFFFu) * N_HID + f4];
            vb = make_float4(bf2f(v.x), bf2f(v.y), bf2f(v.z), bf2f(v.w));
        }
        if (ic < i1) {
            unsigned e = edges[ic];
            wc = __uint_as_float(e & 0xFFFF0000u);
            ushort4 v = *(const ushort4*)&hwb[(long)(e & 0xFFFFu) * N_HID + f4];
            vc = make_float4(bf2f(v.x), bf2f(v.y), bf2f(v.z), bf2f(v.w));
        }
        if (id < i1) {
            unsigned e = edges[id];
            wd = __uint_as_float(e & 0xFFFF0000u);
            ushort4 v = *(const ushort4*)&hwb[(long)(e & 0xFFFFu) * N_HID + f4];
            vd = make_float4(bf2f(v.x), bf2f(v.y), bf2f(v.z), bf2f(v.w));
        }
        fma4(acc, wa, va);
        fma4(acc, wb, vb);
        fma4(acc, wc, vc);
        fma4(acc, wd, vd);
    }
    acc.x += __shfl_xor(acc.x, 16); acc.y += __shfl_xor(acc.y, 16);
    acc.z += __shfl_xor(acc.z, 16); acc.w += __shfl_xor(acc.w, 16);
    acc.x += __shfl_xor(acc.x, 32); acc.y += __shfl_xor(acc.y, 32);
    acc.z += __shfl_xor(acc.z, 32); acc.w += __shfl_xor(acc.w, 32);
    return acc;
}

// ---------- K4: agg1 + b1 + relu + gemm2 fused -> bf16 hwb2, grid-stride ----------
// w2 staged TRANSPOSED in LDS with XOR bank swizzle: word = c*64 + (k ^ ((c&7)<<2)).
// Lane reads its column as 16x ds_read_b128 at the LDS data-rate floor.
__global__ __launch_bounds__(256) void agg1_gemm2(const unsigned short* __restrict__ hwb,
                                                  const unsigned* __restrict__ edges,
                                                  const int* __restrict__ start,
                                                  const float* __restrict__ b1,
                                                  const float* __restrict__ w2,
                                                  unsigned short* __restrict__ hwb2) {
    __shared__ float lw2t[N_HID * N_HID];      // 16 KB, swizzled transpose
    __shared__ float hrow[4][N_HID];           // 1 KB
    int tid = threadIdx.x;
    for (int idx = tid; idx < N_HID * N_HID; idx += 256) {
        int k = idx >> 6, c = idx & 63;        // w2[k][c], coalesced read
        lw2t[c * N_HID + (k ^ ((c & 7) << 2))] = w2[idx];
    }
    __syncthreads();

    int lane = tid & 63;
    int wv = tid >> 6;
    int es = lane >> 4;
    int f4 = (lane & 15) * 4;
    float4 bias = *(const float4*)&b1[f4];
    const float* colp = &lw2t[lane * N_HID];
    int swz = (lane & 7) << 2;

    for (int n = blockIdx.x * 4 + wv; n < N_NODES; n += AGG_B * 4) {
        float4 acc = agg_core(hwb, edges, start[n], start[n + 1], es, f4);
        if (es == 0) {
            acc.x = fmaxf(acc.x + bias.x, 0.f);
            acc.y = fmaxf(acc.y + bias.y, 0.f);
            acc.z = fmaxf(acc.z + bias.z, 0.f);
            acc.w = fmaxf(acc.w + bias.w, 0.f);
            *(float4*)&hrow[wv][f4] = acc;     // intra-wave LDS handoff (in-order DS)
        }
        float oa = 0.f, ob = 0.f;
#pragma unroll
        for (int k4 = 0; k4 < N_HID / 4; k4 += 2) {
            float4 h0 = *(const float4*)&hrow[wv][k4 * 4];
            float4 h1 = *(const float4*)&hrow[wv][k4 * 4 + 4];
            float4 w0 = *(const float4*)&colp[(k4 * 4) ^ swz];
            float4 w1 = *(const float4*)&colp[(k4 * 4 + 4) ^ swz];
            oa = fmaf(h0.x, w0.x, oa); oa = fmaf(h0.y, w0.y, oa);
            oa = fmaf(h0.z, w0.z, oa); oa = fmaf(h0.w, w0.w, oa);
            ob = fmaf(h1.x, w1.x, ob); ob = fmaf(h1.y, w1.y, ob);
            ob = fmaf(h1.z, w1.z, ob); ob = fmaf(h1.w, w1.w, ob);
        }
        hwb2[(long)n * N_HID + lane] = f2bf(oa + ob);
    }
}

// ---------- K5: agg2 + b2 -> out (f32), grid-stride ----------
__global__ __launch_bounds__(256) void agg_out(const unsigned short* __restrict__ hwb2,
                                               const unsigned* __restrict__ edges,
                                               const int* __restrict__ start,
                                               const float* __restrict__ b2,
                                               float* __restrict__ o) {
    int tid = threadIdx.x;
    int lane = tid & 63;
    int es = lane >> 4;
    int f4 = (lane & 15) * 4;
    float4 bias = *(const float4*)&b2[f4];
    for (int n = blockIdx.x * 4 + (tid >> 6); n < N_NODES; n += AGG_B * 4) {
        float4 acc = agg_core(hwb2, edges, start[n], start[n + 1], es, f4);
        if (es == 0) {
            acc.x += bias.x; acc.y += bias.y; acc.z += bias.z; acc.w += bias.w;
            *(float4*)&o[(long)n * N_HID + f4] = acc;
        }
    }
}

extern "C" void kernel_launch(void* const* d_in, const int* in_sizes, int n_in,
                              void* d_out, int out_size, void* d_ws, size_t ws_size,
                              hipStream_t stream) {
    const float* x  = (const float*)d_in[0];
    const int*   ei = (const int*)d_in[1];   // [2, E] flat: src then dst
    const float* ew = (const float*)d_in[2];
    const float* w1 = (const float*)d_in[3];
    const float* b1 = (const float*)d_in[4];
    const float* w2 = (const float*)d_in[5];
    const float* b2 = (const float*)d_in[6];
    float* out = (float*)d_out;

    const int* src = ei;
    const int* dst = ei + N_EDGES;

    char* ws = (char*)d_ws;
    unsigned short* hwb  = (unsigned short*)ws;                      // 6.4 MB
    unsigned short* hwb2 = (unsigned short*)(ws + (size_t)7  * 1024 * 1024); // 6.4 MB
    uint2*    slab  = (uint2*)   (ws + (size_t)14 * 1024 * 1024);    // 6.4 MB
    unsigned* edges = (unsigned*)(ws + (size_t)21 * 1024 * 1024);    // 3.2 MB
    int*      start = (int*)     (ws + (size_t)25 * 1024 * 1024);    // 50001 ints
    int*      cnt   = start + N_NODES + 8;                           // NB1*NBKT
    int*      cnt_t = cnt + NB1 * NBKT;                              // NBKT*NB1

    dim3 blk(256);

    // K1: hist blocks first, then gemm1 blocks (one launch, parallel)
    gemm1_hist<<<dim3(NB1 + GG), blk, 0, stream>>>(x, w1, hwb, dst, cnt, cnt_t);
    // K2: bucket partition (self-computed offsets)
    binscatter<<<dim3(NB1), blk, 0, stream>>>(src, dst, ew, cnt, cnt_t, slab);
    // K3: per-bucket dst sort -> packed edges + start[]
    sort_bucket<<<dim3(NBKT), dim3(512), 0, stream>>>(slab, cnt_t, edges, start);
    // K4: agg1 + b1 + relu + gemm2 -> bf16 hwb2 (h never leaves LDS)
    agg1_gemm2<<<dim3(AGG_B), blk, 0, stream>>>(hwb, edges, start, b1, w2, hwb2);
    // K5: agg2 + b2 -> out
    agg_out<<<dim3(AGG_B), blk, 0, stream>>>(hwb2, edges, start, b2, out);
}

// Round 15
// 112.191 us; speedup vs baseline: 6.8150x; 1.2810x over previous
//
#include <hip/hip_runtime.h>

#define N_NODES 50000
#define N_EDGES 800000
#define N_FEAT  128
#define N_HID   64

#define BKT_LOG 9
#define BKT_SZ  512                                  // nodes per bucket
#define NBKT    ((N_NODES + BKT_SZ - 1) / BKT_SZ)    // 98
#define CH      4096                                 // edges per partition block
#define NB1     ((N_EDGES + CH - 1) / CH)            // 196
#define GROWS   64                                   // rows per gemm block
#define GG      ((N_NODES + GROWS - 1) / GROWS)      // 782 gemm blocks
#define AGG_B   2048                                 // agg grid (grid-stride)

__device__ inline void fma4(float4& acc, float s, const float4& w) {
    acc.x = fmaf(s, w.x, acc.x);
    acc.y = fmaf(s, w.y, acc.y);
    acc.z = fmaf(s, w.z, acc.z);
    acc.w = fmaf(s, w.w, acc.w);
}

__device__ inline unsigned short f2bf(float f) {          // RNE f32 -> bf16
    unsigned u = __float_as_uint(f);
    u = u + 0x7FFFu + ((u >> 16) & 1u);
    return (unsigned short)(u >> 16);
}

__device__ inline int wave_incl_scan(int v) {
    int lane = threadIdx.x & 63;
#pragma unroll
    for (int o = 1; o < 64; o <<= 1) {
        int u = __shfl_up(v, o);
        if (lane >= o) v += u;
    }
    return v;
}

// decode 8 bf16 (uint4) with weight-fma into two float4 accumulators
__device__ inline void fma_bf8(float4& lo, float4& hi, float w, const uint4& v) {
    lo.x = fmaf(w, __uint_as_float(v.x << 16), lo.x);
    lo.y = fmaf(w, __uint_as_float(v.x & 0xFFFF0000u), lo.y);
    lo.z = fmaf(w, __uint_as_float(v.y << 16), lo.z);
    lo.w = fmaf(w, __uint_as_float(v.y & 0xFFFF0000u), lo.w);
    hi.x = fmaf(w, __uint_as_float(v.z << 16), hi.x);
    hi.y = fmaf(w, __uint_as_float(v.z & 0xFFFF0000u), hi.y);
    hi.z = fmaf(w, __uint_as_float(v.w << 16), hi.z);
    hi.w = fmaf(w, __uint_as_float(v.w & 0xFFFF0000u), hi.w);
}

// ---------- gemm core (f32 A): 2 rows x 8 cols per thread, 64 rows/block ----------
template <int K>
__device__ inline void gemm_body(const float* __restrict__ a, const float* __restrict__ lw,
                                 unsigned short* __restrict__ o, int blk) {
    int tid = threadIdx.x;
    int rp = tid >> 3;                 // 0..31
    int c0 = (tid & 7) * 8;            // 0,8,...,56
    int row0 = blk * GROWS + rp * 2;
    if (row0 >= N_NODES) return;
    bool two = (row0 + 1) < N_NODES;

    const float* a0 = a + (long)row0 * K;
    const float* a1 = two ? (a0 + K) : a0;

    float4 aA0 = make_float4(0.f, 0.f, 0.f, 0.f), aA1 = aA0;
    float4 aB0 = aA0, aB1 = aA0;

#pragma unroll 4
    for (int k4 = 0; k4 < K / 4; ++k4) {
        float4 xa = *(const float4*)(a0 + k4 * 4);
        float4 xb = *(const float4*)(a1 + k4 * 4);
#pragma unroll
        for (int j = 0; j < 4; ++j) {
            const float* wk = &lw[(k4 * 4 + j) * N_HID + c0];
            float4 w0 = *(const float4*)(wk);
            float4 w1 = *(const float4*)(wk + 4);
            float sa = (j == 0) ? xa.x : (j == 1) ? xa.y : (j == 2) ? xa.z : xa.w;
            float sb = (j == 0) ? xb.x : (j == 1) ? xb.y : (j == 2) ? xb.z : xb.w;
            fma4(aA0, sa, w0); fma4(aA1, sa, w1);
            fma4(aB0, sb, w0); fma4(aB1, sb, w1);
        }
    }

    unsigned short* op = o + (long)row0 * N_HID + c0;
    *(ushort4*)op = make_ushort4(f2bf(aA0.x), f2bf(aA0.y), f2bf(aA0.z), f2bf(aA0.w));
    *(ushort4*)(op + 4) = make_ushort4(f2bf(aA1.x), f2bf(aA1.y), f2bf(aA1.z), f2bf(aA1.w));
    if (two) {
        *(ushort4*)(op + N_HID) = make_ushort4(f2bf(aB0.x), f2bf(aB0.y), f2bf(aB0.z), f2bf(aB0.w));
        *(ushort4*)(op + N_HID + 4) = make_ushort4(f2bf(aB1.x), f2bf(aB1.y), f2bf(aB1.z), f2bf(aB1.w));
    }
}

// ---------- K1: gemm1 (x@w1 -> bf16 hwb) fused with binhist ----------
__global__ __launch_bounds__(256) void gemm1_hist(const float* __restrict__ a,
                                                  const float* __restrict__ w,
                                                  unsigned short* __restrict__ o,
                                                  const int* __restrict__ dst,
                                                  int* __restrict__ cnt,
                                                  int* __restrict__ cnt_t) {
    __shared__ float lw[N_FEAT * N_HID];        // 32 KB
    int tid = threadIdx.x;
    if (blockIdx.x < NB1) {                      // ---- histogram part ----
        int* h = (int*)lw;                       // reuse LDS
        int bid = blockIdx.x;
        if (tid < NBKT) h[tid] = 0;
        __syncthreads();
        int e0 = bid * CH;
        for (int i = tid; i < CH; i += 256) {
            int e = e0 + i;
            if (e < N_EDGES) atomicAdd(&h[dst[e] >> BKT_LOG], 1);
        }
        __syncthreads();
        if (tid < NBKT) {
            int v = h[tid];
            cnt[bid * NBKT + tid] = v;
            cnt_t[tid * NB1 + bid] = v;
        }
        return;
    }
    // ---- gemm part ----
    for (int idx = tid * 4; idx < N_FEAT * N_HID; idx += 256 * 4)
        *(float4*)&lw[idx] = *(const float4*)&w[idx];
    __syncthreads();
    gemm_body<N_FEAT>(a, lw, o, blockIdx.x - NB1);
}

// ---------- K5: gemm2 with bf16 A (h) -> bf16 hwb2 ----------
__global__ __launch_bounds__(256) void gemm2_bf16(const unsigned short* __restrict__ a,
                                                  const float* __restrict__ w,
                                                  unsigned short* __restrict__ o) {
    __shared__ float lw[N_HID * N_HID];          // 16 KB
    int tid = threadIdx.x;
    for (int idx = tid * 4; idx < N_HID * N_HID; idx += 256 * 4)
        *(float4*)&lw[idx] = *(const float4*)&w[idx];
    __syncthreads();

    int rp = tid >> 3;
    int c0 = (tid & 7) * 8;
    int row0 = blockIdx.x * GROWS + rp * 2;
    if (row0 >= N_NODES) return;
    bool two = (row0 + 1) < N_NODES;

    const unsigned short* a0 = a + (long)row0 * N_HID;
    const unsigned short* a1 = two ? (a0 + N_HID) : a0;

    float4 aA0 = make_float4(0.f, 0.f, 0.f, 0.f), aA1 = aA0;
    float4 aB0 = aA0, aB1 = aA0;

#pragma unroll 2
    for (int k8 = 0; k8 < N_HID / 8; ++k8) {
        uint4 xa = *(const uint4*)(a0 + k8 * 8);
        uint4 xb = *(const uint4*)(a1 + k8 * 8);
        float sa[8], sb[8];
        sa[0] = __uint_as_float(xa.x << 16); sa[1] = __uint_as_float(xa.x & 0xFFFF0000u);
        sa[2] = __uint_as_float(xa.y << 16); sa[3] = __uint_as_float(xa.y & 0xFFFF0000u);
        sa[4] = __uint_as_float(xa.z << 16); sa[5] = __uint_as_float(xa.z & 0xFFFF0000u);
        sa[6] = __uint_as_float(xa.w << 16); sa[7] = __uint_as_float(xa.w & 0xFFFF0000u);
        sb[0] = __uint_as_float(xb.x << 16); sb[1] = __uint_as_float(xb.x & 0xFFFF0000u);
        sb[2] = __uint_as_float(xb.y << 16); sb[3] = __uint_as_float(xb.y & 0xFFFF0000u);
        sb[4] = __uint_as_float(xb.z << 16); sb[5] = __uint_as_float(xb.z & 0xFFFF0000u);
        sb[6] = __uint_as_float(xb.w << 16); sb[7] = __uint_as_float(xb.w & 0xFFFF0000u);
#pragma unroll
        for (int j = 0; j < 8; ++j) {
            const float* wk = &lw[(k8 * 8 + j) * N_HID + c0];
            float4 w0 = *(const float4*)(wk);
            float4 w1 = *(const float4*)(wk + 4);
            fma4(aA0, sa[j], w0); fma4(aA1, sa[j], w1);
            fma4(aB0, sb[j], w0); fma4(aB1, sb[j], w1);
        }
    }

    unsigned short* op = o + (long)row0 * N_HID + c0;
    *(ushort4*)op = make_ushort4(f2bf(aA0.x), f2bf(aA0.y), f2bf(aA0.z), f2bf(aA0.w));
    *(ushort4*)(op + 4) = make_ushort4(f2bf(aA1.x), f2bf(aA1.y), f2bf(aA1.z), f2bf(aA1.w));
    if (two) {
        *(ushort4*)(op + N_HID) = make_ushort4(f2bf(aB0.x), f2bf(aB0.y), f2bf(aB0.z), f2bf(aB0.w));
        *(ushort4*)(op + N_HID + 4) = make_ushort4(f2bf(aB1.x), f2bf(aB1.y), f2bf(aB1.z), f2bf(aB1.w));
    }
}

// ---------- K2: binscatter, self-computing cursor bases ----------
__global__ __launch_bounds__(256) void binscatter(const int* __restrict__ src,
                                                  const int* __restrict__ dst,
                                                  const float* __restrict__ ew,
                                                  const int* __restrict__ cnt,
                                                  const int* __restrict__ cnt_t,
                                                  uint2* __restrict__ slab) {
    __shared__ int cur[NBKT];
    __shared__ int wtot[2];
    int t = threadIdx.x;
    int b = blockIdx.x;

    int tot = 0, pre = 0;
    if (t < NBKT) {
        const int4* p = (const int4*)(cnt_t + t * NB1);   // NB1 % 4 == 0
        for (int q = 0; q < NB1 / 4; ++q) {
            int4 v = p[q];
            tot += v.x + v.y + v.z + v.w;
        }
        int p0 = 0, p1 = 0, p2 = 0, p3 = 0;
        int j = 0;
        for (; j + 4 <= b; j += 4) {
            p0 += cnt[(j + 0) * NBKT + t];
            p1 += cnt[(j + 1) * NBKT + t];
            p2 += cnt[(j + 2) * NBKT + t];
            p3 += cnt[(j + 3) * NBKT + t];
        }
        for (; j < b; ++j) p0 += cnt[j * NBKT + t];
        pre = p0 + p1 + p2 + p3;
    }
    int incl = wave_incl_scan(tot);                   // waves 0,1 cover t<98
    if (t < 128 && (t & 63) == 63) wtot[t >> 6] = incl;
    __syncthreads();
    if (t < NBKT) {
        int bstart_t = (t >= 64 ? wtot[0] : 0) + incl - tot;  // exclusive prefix
        cur[t] = bstart_t + pre;
    }
    __syncthreads();

    int e0 = b * CH;
    for (int i = t; i < CH; i += 256) {
        int e = e0 + i;
        if (e >= N_EDGES) continue;
        int d = dst[e];
        int bin = d >> BKT_LOG;
        int p = atomicAdd(&cur[bin], 1);
        slab[p] = make_uint2((unsigned)src[e] | ((unsigned)(d & (BKT_SZ - 1)) << 16),
                             __float_as_uint(ew[e]));
    }
}

// ---------- K3: per-bucket counting sort (self-computed bstart, wave scans) ----------
__global__ __launch_bounds__(512) void sort_bucket(const uint2* __restrict__ slab,
                                                   const int* __restrict__ cnt_t,
                                                   unsigned* __restrict__ edges,
                                                   int* __restrict__ start) {
    __shared__ int tt[NBKT];
    __shared__ int h[BKT_SZ];
    __shared__ int wtot[8];
    __shared__ int bs[2];
    int b = blockIdx.x;
    int t = threadIdx.x;
    int lane = t & 63;
    int w = t >> 6;

    if (t < NBKT) {
        int s = 0;
        const int4* p = (const int4*)(cnt_t + t * NB1);
        for (int q = 0; q < NB1 / 4; ++q) {
            int4 v = p[q];
            s += v.x + v.y + v.z + v.w;
        }
        tt[t] = s;
    }
    __syncthreads();
    if (t < 64) {
        int v = (t < b ? tt[t] : 0) + (t + 64 < b ? tt[t + 64] : 0);
#pragma unroll
        for (int o = 32; o >= 1; o >>= 1) v += __shfl_xor(v, o);
        if (t == 0) { bs[0] = v; bs[1] = tt[b]; }
    }
    __syncthreads();
    int base = bs[0];
    int c = bs[1];

    h[t] = 0;
    __syncthreads();
    for (int i = t; i < c; i += 512)
        atomicAdd(&h[(slab[base + i].x >> 16) & (BKT_SZ - 1)], 1);
    __syncthreads();

    int v = h[t];
    int incl = wave_incl_scan(v);
    if (lane == 63) wtot[w] = incl;
    __syncthreads();
    int add = 0;
#pragma unroll
    for (int i = 0; i < 8; ++i) add += (i < w) ? wtot[i] : 0;
    int excl = add + incl - v;

    int g = (b << BKT_LOG) + t;
    if (g < N_NODES) start[g] = base + excl;
    if (b == NBKT - 1 && t == 0) start[N_NODES] = N_EDGES;

    h[t] = base + excl;                   // reuse as cursor
    __syncthreads();
    for (int i = t; i < c; i += 512) {
        uint2 r = slab[base + i];
        int p = atomicAdd(&h[(r.x >> 16) & (BKT_SZ - 1)], 1);
        edges[p] = (r.x & 0xFFFFu) | ((unsigned)f2bf(__uint_as_float(r.y)) << 16);
    }
}

// ---------- agg core v5: 16 edges in flight, 16B gathers (8 lanes/edge) ----------
// lane = es*8 + f8g : es = edge slot (0..7), f8g = feature group (8 feats each)
__device__ inline void agg_core8(const unsigned short* __restrict__ hwb,
                                 const unsigned* __restrict__ edges,
                                 int i0, int i1, int es, int f8,
                                 float4& lo, float4& hi) {
    lo = make_float4(0.f, 0.f, 0.f, 0.f);
    hi = lo;
    for (int base = i0; base < i1; base += 16) {
        int ia = base + es;
        int ib = base + 8 + es;
        float wa = 0.f, wb = 0.f;
        uint4 va = make_uint4(0u, 0u, 0u, 0u), vb = va;
        if (ia < i1) {                        // uniform per 8-lane group
            unsigned e = edges[ia];
            wa = __uint_as_float(e & 0xFFFF0000u);
            va = *(const uint4*)&hwb[(long)(e & 0xFFFFu) * N_HID + f8];
        }
        if (ib < i1) {
            unsigned e = edges[ib];
            wb = __uint_as_float(e & 0xFFFF0000u);
            vb = *(const uint4*)&hwb[(long)(e & 0xFFFFu) * N_HID + f8];
        }
        fma_bf8(lo, hi, wa, va);
        fma_bf8(lo, hi, wb, vb);
    }
    // reduce across the 8 edge slots (lane bits 3,4,5)
#pragma unroll
    for (int m = 8; m <= 32; m <<= 1) {
        lo.x += __shfl_xor(lo.x, m); lo.y += __shfl_xor(lo.y, m);
        lo.z += __shfl_xor(lo.z, m); lo.w += __shfl_xor(lo.w, m);
        hi.x += __shfl_xor(hi.x, m); hi.y += __shfl_xor(hi.y, m);
        hi.z += __shfl_xor(hi.z, m); hi.w += __shfl_xor(hi.w, m);
    }
}

// ---------- K4: agg1 + b1 + relu -> h (bf16), grid-stride ----------
__global__ __launch_bounds__(256) void agg_relu(const unsigned short* __restrict__ hwb,
                                                const unsigned* __restrict__ edges,
                                                const int* __restrict__ start,
                                                const float* __restrict__ b1,
                                                unsigned short* __restrict__ hb) {
    int tid = threadIdx.x;
    int lane = tid & 63;
    int es = lane >> 3;
    int f8 = (lane & 7) * 8;
    float4 bl = *(const float4*)&b1[f8];
    float4 bh = *(const float4*)&b1[f8 + 4];
    for (int n = blockIdx.x * 4 + (tid >> 6); n < N_NODES; n += AGG_B * 4) {
        float4 lo, hi;
        agg_core8(hwb, edges, start[n], start[n + 1], es, f8, lo, hi);
        if (es == 0) {
            lo.x = fmaxf(lo.x + bl.x, 0.f); lo.y = fmaxf(lo.y + bl.y, 0.f);
            lo.z = fmaxf(lo.z + bl.z, 0.f); lo.w = fmaxf(lo.w + bl.w, 0.f);
            hi.x = fmaxf(hi.x + bh.x, 0.f); hi.y = fmaxf(hi.y + bh.y, 0.f);
            hi.z = fmaxf(hi.z + bh.z, 0.f); hi.w = fmaxf(hi.w + bh.w, 0.f);
            uint4 p;
            p.x = (unsigned)f2bf(lo.x) | ((unsigned)f2bf(lo.y) << 16);
            p.y = (unsigned)f2bf(lo.z) | ((unsigned)f2bf(lo.w) << 16);
            p.z = (unsigned)f2bf(hi.x) | ((unsigned)f2bf(hi.y) << 16);
            p.w = (unsigned)f2bf(hi.z) | ((unsigned)f2bf(hi.w) << 16);
            *(uint4*)&hb[(long)n * N_HID + f8] = p;
        }
    }
}

// ---------- K6: agg2 + b2 -> out (f32), grid-stride ----------
__global__ __launch_bounds__(256) void agg_out(const unsigned short* __restrict__ hwb2,
                                               const unsigned* __restrict__ edges,
                                               const int* __restrict__ start,
                                               const float* __restrict__ b2,
                                               float* __restrict__ o) {
    int tid = threadIdx.x;
    int lane = tid & 63;
    int es = lane >> 3;
    int f8 = (lane & 7) * 8;
    float4 bl = *(const float4*)&b2[f8];
    float4 bh = *(const float4*)&b2[f8 + 4];
    for (int n = blockIdx.x * 4 + (tid >> 6); n < N_NODES; n += AGG_B * 4) {
        float4 lo, hi;
        agg_core8(hwb2, edges, start[n], start[n + 1], es, f8, lo, hi);
        if (es == 0) {
            lo.x += bl.x; lo.y += bl.y; lo.z += bl.z; lo.w += bl.w;
            hi.x += bh.x; hi.y += bh.y; hi.z += bh.z; hi.w += bh.w;
            *(float4*)&o[(long)n * N_HID + f8] = lo;
            *(float4*)&o[(long)n * N_HID + f8 + 4] = hi;
        }
    }
}

extern "C" void kernel_launch(void* const* d_in, const int* in_sizes, int n_in,
                              void* d_out, int out_size, void* d_ws, size_t ws_size,
                              hipStream_t stream) {
    const float* x  = (const float*)d_in[0];
    const int*   ei = (const int*)d_in[1];   // [2, E] flat: src then dst
    const float* ew = (const float*)d_in[2];
    const float* w1 = (const float*)d_in[3];
    const float* b1 = (const float*)d_in[4];
    const float* w2 = (const float*)d_in[5];
    const float* b2 = (const float*)d_in[6];
    float* out = (float*)d_out;

    const int* src = ei;
    const int* dst = ei + N_EDGES;

    char* ws = (char*)d_ws;
    unsigned short* hwb  = (unsigned short*)ws;                      // 6.4 MB
    unsigned short* hwb2 = (unsigned short*)(ws + (size_t)7  * 1024 * 1024); // 6.4 MB
    unsigned short* hb   = (unsigned short*)(ws + (size_t)14 * 1024 * 1024); // 6.4 MB (bf16 h)
    uint2*    slab  = (uint2*)   (ws + (size_t)21 * 1024 * 1024);    // 6.4 MB
    unsigned* edges = (unsigned*)(ws + (size_t)28 * 1024 * 1024);    // 3.2 MB
    int*      start = (int*)     (ws + (size_t)32 * 1024 * 1024);    // 50001 ints
    int*      cnt   = start + N_NODES + 8;                           // NB1*NBKT
    int*      cnt_t = cnt + NB1 * NBKT;                              // NBKT*NB1

    dim3 blk(256);

    // K1: hist blocks first, then gemm1 blocks (one launch, parallel)
    gemm1_hist<<<dim3(NB1 + GG), blk, 0, stream>>>(x, w1, hwb, dst, cnt, cnt_t);
    // K2: bucket partition (self-computed offsets)
    binscatter<<<dim3(NB1), blk, 0, stream>>>(src, dst, ew, cnt, cnt_t, slab);
    // K3: per-bucket dst sort -> packed edges + start[]
    sort_bucket<<<dim3(NBKT), dim3(512), 0, stream>>>(slab, cnt_t, edges, start);
    // K4: agg1 + b1 + relu -> h (bf16)
    agg_relu<<<dim3(AGG_B), blk, 0, stream>>>(hwb, edges, start, b1, hb);
    // K5: gemm2: h(bf16) @ w2 -> bf16 hwb2
    gemm2_bf16<<<dim3(GG), blk, 0, stream>>>(hb, w2, hwb2);
    // K6: agg2 + b2 -> out
    agg_out<<<dim3(AGG_B), blk, 0, stream>>>(hwb2, edges, start, b2, out);
}